// Round 1
// baseline (361.100 us; speedup 1.0000x reference)
//
#include <hip/hip_runtime.h>
#include <cstdint>
#include <cstddef>

#define T_TOK 64
#define K_IN 4096
#define N_OUT 14336
#define SPLITK 4
#define KTOTAL 1024                  // K per block (4096/4)
#define KCHUNK 256                   // K per A-stage chunk
#define BK 32                        // k-rows per B stage
#define NSTAGES 32                   // KTOTAL / BK
#define NCOLS 64                     // cols per block (16 per wave)
#define DEPTH 4                      // B ring slots per wave
#define A_BYTES 32768                // 64 rows x 512 B, XOR-swizzled (no pad)
#define B_WAVE_BYTES (DEPTH * BK * 16 * 4)   // 8192 per wave
#define LDS_TOTAL (A_BYTES + 4 * B_WAVE_BYTES)  // 65536

typedef __attribute__((ext_vector_type(8))) short bf16x8;
typedef __attribute__((ext_vector_type(4))) float f32x4;

static __device__ __forceinline__ unsigned short bf16_rne(float f) {
    unsigned u = __builtin_bit_cast(unsigned, f);
    unsigned r = (u + 0x7fffu + ((u >> 16) & 1u)) >> 16;
    return (unsigned short)r;
}

// Kernel 1: x (fp32) -> bf16 copy in ws + per-token partial row sums.
// 256 blocks (4 per token) so all CUs participate; init sums the 4 partials.
__global__ __launch_bounds__(256) void prep_kernel(const float* __restrict__ x,
                                                   unsigned short* __restrict__ xbf,
                                                   float* __restrict__ rowsum4) {
    const int b = blockIdx.x;           // token = b>>2, quarter = b&3
    const int row = b >> 2;
    const int qtr = b & 3;
    const int t = threadIdx.x;
    const int idx = qtr * 256 + t;      // float4 index within the row
    float4 v = ((const float4*)(x + (size_t)row * K_IN))[idx];
    float s = v.x + v.y + v.z + v.w;
    ushort4 h;
    h.x = bf16_rne(v.x); h.y = bf16_rne(v.y);
    h.z = bf16_rne(v.z); h.w = bf16_rne(v.w);
    *(ushort4*)(xbf + (size_t)row * K_IN + (size_t)idx * 4) = h;
#pragma unroll
    for (int off = 32; off > 0; off >>= 1) s += __shfl_down(s, off, 64);
    __shared__ float part[4];
    const int wave = t >> 6, lane = t & 63;
    if (lane == 0) part[wave] = s;
    __syncthreads();
    if (t == 0) rowsum4[b] = part[0] + part[1] + part[2] + part[3];
}

// Kernel 2: initialize out with bias + rowsum*u. Grid (N_OUT/4/256, T_TOK).
__global__ __launch_bounds__(256) void init_kernel(const float* __restrict__ rowsum4,
                                                   const float* __restrict__ u,
                                                   const float* __restrict__ bias,
                                                   float* __restrict__ out) {
    const int t = blockIdx.y;
    const int n4 = blockIdx.x * 256 + threadIdx.x;
    const float rs = rowsum4[t * 4 + 0] + rowsum4[t * 4 + 1] +
                     rowsum4[t * 4 + 2] + rowsum4[t * 4 + 3];
    float4 b = ((const float4*)bias)[n4];
    float4 uu = ((const float4*)u)[n4];
    float4 o;
    o.x = b.x + rs * uu.x; o.y = b.y + rs * uu.y;
    o.z = b.z + rs * uu.z; o.w = b.w + rs * uu.w;
    ((float4*)(out + (size_t)t * N_OUT))[n4] = o;
}

// Kernel 3: split-K int4-dequant GEMM, BARRIER-FREE DMA ring, SPLITK=4.
// Grid (224, 4) x 256 thr. Block = 64 cols x 1024 k, processed as 4 chunks of
// 256 k. B is DMA'd (global_load_lds) into a per-wave depth-4 LDS ring; the
// wave syncs on its own queue with counted s_waitcnt vmcnt(N) (never 0 in the
// steady loop). A (64 tok x 256 k bf16, 32 KB) is re-staged per chunk: the
// next chunk's A is preloaded into VGPRs mid-chunk (8 dwordx4 entering the
// vmcnt queue -> WN=14 for the 4 stages where they're in flight), and chunk
// boundaries use raw s_barrier + lgkmcnt(0) only, so the B ring never drains.
// Atomics per output: 4 (was 16).
__global__ __launch_bounds__(256) void gemm_kernel(const unsigned short* __restrict__ xbf,
                                                   const int* __restrict__ W,
                                                   const float* __restrict__ scales,
                                                   float* __restrict__ out) {
    __shared__ char lds[LDS_TOTAL];
    char* Alds = lds;

    const int tid = threadIdx.x;
    const int wave = tid >> 6;
    const int lane = tid & 63;
    const int q = lane >> 4;            // quad: k-offset q*8 in frags
    const int r = lane & 15;            // col within wave strip / token row
    const int cb = blockIdx.x;
    const int kbase = blockIdx.y * KTOTAL;
    const int col = cb * NCOLS + wave * 16 + r;

    // 8 x 128-group scales covering this block's 1024-k range (loaded before
    // the initial __syncthreads, whose full drain retires them).
    const int g0 = kbase >> 7;
    float sc[8];
#pragma unroll
    for (int i = 0; i < 8; i++) sc[i] = scales[(size_t)(g0 + i) * N_OUT + col];

    // A chunk staging: 64 rows x 512 B, 16-B chunk cc stored at cc^(row&7)
    int4 av[8];
    auto load_A = [&](int c) {
#pragma unroll
        for (int i = 0; i < 8; i++) {
            const int chunk = i * 256 + tid;           // 2048 chunks of 16 B
            const int row = chunk >> 5;
            const int cc = chunk & 31;
            av[i] = *(const int4*)(xbf + (size_t)row * K_IN + kbase + c * KCHUNK + cc * 8);
        }
    };
    auto store_A = [&]() {
#pragma unroll
        for (int i = 0; i < 8; i++) {
            const int chunk = i * 256 + tid;
            const int row = chunk >> 5;
            const int cc = chunk & 31;
            *(int4*)(Alds + row * 512 + (cc ^ (row & 7)) * 16) = av[i];
        }
    };

    load_A(0);
    store_A();
    __syncthreads();   // full drain once: sc + av retired, A0 visible

    char* Bring = lds + A_BYTES + wave * B_WAVE_BYTES;

    // per-wave B DMA: stage = 16 cols x 32 k = 2 KB = 2 instrs x 1 KB.
    // lane -> (k_local = lane>>2, colq = lane&3); LDS dest = base + lane*16.
    auto issue_stage = [&](int S) {
        char* slot = Bring + (S & 3) * (BK * 64);
#pragma unroll
        for (int j = 0; j < 2; j++) {
            const int krow = kbase + S * BK + j * 16 + (lane >> 2);
            const int* g = W + (size_t)krow * N_OUT + cb * NCOLS + wave * 16 + (lane & 3) * 4;
            void* l = (void*)(slot + j * 1024);
            __builtin_amdgcn_global_load_lds(
                (const __attribute__((address_space(1))) void*)g,
                (__attribute__((address_space(3))) void*)l, 16, 0, 0);
        }
    };

    f32x4 acc[4];
#pragma unroll
    for (int mt = 0; mt < 4; mt++) acc[mt] = f32x4{0.f, 0.f, 0.f, 0.f};

    auto compute_stage = [&](int S, float scs) {
        const char* slot = Bring + (S & 3) * (BK * 64);
        const int sl = S & 7;                       // stage within A chunk
        int bi[8];
#pragma unroll
        for (int jj = 0; jj < 8; jj++)
            bi[jj] = *(const int*)(slot + (q * 8 + jj) * 64 + r * 4);
        bf16x8 bf;
#pragma unroll
        for (int jj = 0; jj < 8; jj++) bf[jj] = (short)bf16_rne((float)bi[jj] * scs);
#pragma unroll
        for (int mt = 0; mt < 4; mt++) {
            const int row = r + mt * 16;
            bf16x8 af = *(const bf16x8*)(Alds + row * 512 + (((sl * 4 + q) ^ (r & 7)) * 16));
            acc[mt] = __builtin_amdgcn_mfma_f32_16x16x32_bf16(af, bf, acc[mt], 0, 0, 0);
        }
    };

    // prologue: fill the ring (8 DMA instrs in flight)
    issue_stage(0); issue_stage(1); issue_stage(2); issue_stage(3);

    // vmcnt(N): stage S's 2 instrs must be retired before compute_stage(S).
    // WN = instrs issued after stage S (6 = 3 stages; +8 while the next
    // chunk's 8 A-loads sit in the queue). simm16: lgkmcnt=15|expcnt=7|vmcnt.
#define GEMM_STAGE(S, WN)                                    \
    {                                                        \
        __builtin_amdgcn_s_waitcnt(0x0F70 | (WN));           \
        compute_stage((S), sc[(S) >> 2]);                    \
        if ((S) + DEPTH < NSTAGES) issue_stage((S) + DEPTH); \
    }

    // boundary: barrier (all waves done reading old A) -> write new A from
    // regs -> lgkmcnt(0) -> barrier. vmcnt=63 in the wait: B ring stays full.
#define CHUNK_BOUNDARY()                      \
    {                                         \
        __builtin_amdgcn_s_barrier();         \
        __builtin_amdgcn_sched_barrier(0);    \
        store_A();                            \
        __builtin_amdgcn_s_waitcnt(0xC07F);   \
        __builtin_amdgcn_sched_barrier(0);    \
        __builtin_amdgcn_s_barrier();         \
        __builtin_amdgcn_sched_barrier(0);    \
    }

    // chunk 0 (stages 0..7); A1 preload issued after stage 1's issue(5)
    GEMM_STAGE(0, 6) GEMM_STAGE(1, 6)
    load_A(1);
    GEMM_STAGE(2, 14) GEMM_STAGE(3, 14) GEMM_STAGE(4, 14) GEMM_STAGE(5, 14)
    GEMM_STAGE(6, 6) GEMM_STAGE(7, 6)        // wait(6) at s=6 retires av
    CHUNK_BOUNDARY()
    // chunk 1 (stages 8..15)
    GEMM_STAGE(8, 6) GEMM_STAGE(9, 6)
    load_A(2);
    GEMM_STAGE(10, 14) GEMM_STAGE(11, 14) GEMM_STAGE(12, 14) GEMM_STAGE(13, 14)
    GEMM_STAGE(14, 6) GEMM_STAGE(15, 6)
    CHUNK_BOUNDARY()
    // chunk 2 (stages 16..23)
    GEMM_STAGE(16, 6) GEMM_STAGE(17, 6)
    load_A(3);
    GEMM_STAGE(18, 14) GEMM_STAGE(19, 14) GEMM_STAGE(20, 14) GEMM_STAGE(21, 14)
    GEMM_STAGE(22, 6) GEMM_STAGE(23, 6)
    CHUNK_BOUNDARY()
    // chunk 3 (stages 24..31): no A preload, drain tail 6/4/2/0
    GEMM_STAGE(24, 6) GEMM_STAGE(25, 6) GEMM_STAGE(26, 6) GEMM_STAGE(27, 6)
    GEMM_STAGE(28, 6) GEMM_STAGE(29, 4) GEMM_STAGE(30, 2) GEMM_STAGE(31, 0)
#undef GEMM_STAGE
#undef CHUNK_BOUNDARY

    // epilogue: atomic accumulate partials (C/D layout: row = q*4+i, col = col)
#pragma unroll
    for (int mt = 0; mt < 4; mt++) {
#pragma unroll
        for (int i = 0; i < 4; i++) {
            const int t = mt * 16 + q * 4 + i;
            atomicAdd(out + (size_t)t * N_OUT + col, acc[mt][i]);
        }
    }
}

extern "C" void kernel_launch(void* const* d_in, const int* in_sizes, int n_in,
                              void* d_out, int out_size, void* d_ws, size_t ws_size,
                              hipStream_t stream) {
    const float* x      = (const float*)d_in[0];
    const int*   W      = (const int*)d_in[1];
    const float* scales = (const float*)d_in[2];
    const float* u      = (const float*)d_in[3];
    const float* bias   = (const float*)d_in[4];
    float* out = (float*)d_out;

    unsigned short* xbf = (unsigned short*)d_ws;                          // 64*4096*2 = 512 KB
    float* rowsum4 = (float*)((char*)d_ws + (size_t)T_TOK * K_IN * 2);    // 256 floats

    prep_kernel<<<T_TOK * 4, 256, 0, stream>>>(x, xbf, rowsum4);
    init_kernel<<<dim3(N_OUT / 4 / 256, T_TOK), 256, 0, stream>>>(rowsum4, u, bias, out);
    gemm_kernel<<<dim3(N_OUT / NCOLS, SPLITK), 256, 0, stream>>>(xbf, W, scales, out);
}

// Round 2
// 344.467 us; speedup vs baseline: 1.0483x; 1.0483x over previous
//
#include <hip/hip_runtime.h>
#include <cstdint>
#include <cstddef>

#define T_TOK 64
#define K_IN 4096
#define N_OUT 14336
#define SPLITK 16
#define KCHUNK 256                   // K per block (4096/16)
#define BK 32                        // k-rows per B stage
#define NSTAGES (KCHUNK / BK)        // 8
#define NCOLS 64                     // cols per block (16 per wave)
#define DEPTH 4                      // B ring slots per wave
#define A_BYTES 32768                // 64 rows x 512 B, XOR-swizzled (no pad)
#define B_WAVE_BYTES (DEPTH * BK * 16 * 4)   // 8192 per wave
#define LDS_TOTAL (A_BYTES + 4 * B_WAVE_BYTES)  // 65536

typedef __attribute__((ext_vector_type(8))) short bf16x8;
typedef __attribute__((ext_vector_type(4))) float f32x4;

static __device__ __forceinline__ unsigned short bf16_rne(float f) {
    unsigned u = __builtin_bit_cast(unsigned, f);
    unsigned r = (u + 0x7fffu + ((u >> 16) & 1u)) >> 16;
    return (unsigned short)r;
}

// Kernel 1: out = bias + rowsum(x_t) * u. Grid (N_OUT/4/256 = 14, T_TOK).
// Each block computes its token's rowsum inline (x row = 16 KB, L2-resident;
// 14x redundancy per token is free). Summation order identical to the old
// prep kernel (i*256+tid float4 indexing + same shuffle tree) -> bit-identical.
__global__ __launch_bounds__(256) void init_kernel(const float* __restrict__ x,
                                                   const float* __restrict__ u,
                                                   const float* __restrict__ bias,
                                                   float* __restrict__ out) {
    const int t = blockIdx.y;
    const int tid = threadIdx.x;
    const float4* x4 = (const float4*)(x + (size_t)t * K_IN);
    float s = 0.f;
#pragma unroll
    for (int i = 0; i < 4; i++) {
        float4 v = x4[i * 256 + tid];
        s += v.x + v.y + v.z + v.w;
    }
#pragma unroll
    for (int off = 32; off > 0; off >>= 1) s += __shfl_down(s, off, 64);
    __shared__ float part[4];
    if ((tid & 63) == 0) part[tid >> 6] = s;
    __syncthreads();
    const float rs = part[0] + part[1] + part[2] + part[3];

    const int n4 = blockIdx.x * 256 + tid;
    float4 b = ((const float4*)bias)[n4];
    float4 uu = ((const float4*)u)[n4];
    float4 o;
    o.x = b.x + rs * uu.x; o.y = b.y + rs * uu.y;
    o.z = b.z + rs * uu.z; o.w = b.w + rs * uu.w;
    ((float4*)(out + (size_t)t * N_OUT))[n4] = o;
}

// Kernel 2: split-K int4-dequant GEMM, BARRIER-FREE K-loop (R0 structure).
// Grid (224, 16) x 256 thr. Block = 64 cols x 256 k; wave owns a private
// 16-col strip. B is DMA'd (global_load_lds) into a per-wave depth-4 LDS ring
// (2 KB/stage); the wave syncs on its own queue with s_waitcnt vmcnt(N)
// (never 0, no __syncthreads in the loop) -> 6 DMA instrs always in flight.
// A is read DIRECTLY from x (fp32), converted to bf16 in-register, staged
// once (64 tok x 256 k bf16, 32 KB, XOR-swizzled), one barrier total.
__global__ __launch_bounds__(256) void gemm_kernel(const float* __restrict__ x,
                                                   const int* __restrict__ W,
                                                   const float* __restrict__ scales,
                                                   float* __restrict__ out) {
    __shared__ char lds[LDS_TOTAL];
    char* Alds = lds;

    const int tid = threadIdx.x;
    const int wave = tid >> 6;
    const int lane = tid & 63;
    const int q = lane >> 4;            // quad: k-offset q*8 in frags
    const int r = lane & 15;            // col within wave strip / token row
    const int cb = blockIdx.x;
    const int kbase = blockIdx.y * KCHUNK;
    const int col = cb * NCOLS + wave * 16 + r;

    // two 128-group scales covering this block's 256-k chunk
    const int g0 = kbase >> 7;
    const float sc0 = scales[(size_t)g0 * N_OUT + col];
    const float sc1 = scales[(size_t)(g0 + 1) * N_OUT + col];

    // ---- stage A once from x fp32: 64 rows x 256 k -> bf16, chunk cc (16 B
    // of bf16 = 8 k) stored at cc^(row&7). 16 float4 loads, 64 cvt per thread.
    {
        float4 av[16];
#pragma unroll
        for (int i = 0; i < 8; i++) {
            const int chunk = i * 256 + tid;           // 2048 chunks of 8 k
            const int row = chunk >> 5;
            const int cc = chunk & 31;
            const float* src = x + (size_t)row * K_IN + kbase + cc * 8;
            av[2 * i]     = *(const float4*)(src);
            av[2 * i + 1] = *(const float4*)(src + 4);
        }
#pragma unroll
        for (int i = 0; i < 8; i++) {
            const int chunk = i * 256 + tid;
            const int row = chunk >> 5;
            const int cc = chunk & 31;
            const float4 a0 = av[2 * i], a1 = av[2 * i + 1];
            ushort4 h0, h1;
            h0.x = bf16_rne(a0.x); h0.y = bf16_rne(a0.y);
            h0.z = bf16_rne(a0.z); h0.w = bf16_rne(a0.w);
            h1.x = bf16_rne(a1.x); h1.y = bf16_rne(a1.y);
            h1.z = bf16_rne(a1.z); h1.w = bf16_rne(a1.w);
            char* dst = Alds + row * 512 + (cc ^ (row & 7)) * 16;
            *(ushort4*)dst = h0;
            *(ushort4*)(dst + 8) = h1;
        }
    }
    __syncthreads();   // ONLY barrier: A visible to all waves (before DMA issues)

    char* Bring = lds + A_BYTES + wave * B_WAVE_BYTES;

    // per-wave B DMA: stage = 16 cols x 32 k = 2 KB = 2 instrs x 1 KB.
    // lane -> (k_local = lane>>2, colq = lane&3); LDS dest = base + lane*16
    // gives [k][col16] rows of 64 B. Global side matches: 64 B per k-row.
    auto issue_stage = [&](int s) {
        char* slot = Bring + (s & 3) * (BK * 64);
#pragma unroll
        for (int j = 0; j < 2; j++) {
            const int krow = kbase + s * BK + j * 16 + (lane >> 2);
            const int* g = W + (size_t)krow * N_OUT + cb * NCOLS + wave * 16 + (lane & 3) * 4;
            void* l = (void*)(slot + j * 1024);
            __builtin_amdgcn_global_load_lds(
                (const __attribute__((address_space(1))) void*)g,
                (__attribute__((address_space(3))) void*)l, 16, 0, 0);
        }
    };

    f32x4 acc[4];
#pragma unroll
    for (int mt = 0; mt < 4; mt++) acc[mt] = f32x4{0.f, 0.f, 0.f, 0.f};

    auto compute_stage = [&](int s) {
        const char* slot = Bring + (s & 3) * (BK * 64);
        const float scs = (s < 4) ? sc0 : sc1;        // group = (kbase+s*32)/128
        int bi[8];
#pragma unroll
        for (int jj = 0; jj < 8; jj++)
            bi[jj] = *(const int*)(slot + (q * 8 + jj) * 64 + r * 4);
        bf16x8 bf;
#pragma unroll
        for (int jj = 0; jj < 8; jj++) bf[jj] = (short)bf16_rne((float)bi[jj] * scs);
#pragma unroll
        for (int mt = 0; mt < 4; mt++) {
            const int row = r + mt * 16;
            bf16x8 af = *(const bf16x8*)(Alds + row * 512 + (((s * 4 + q) ^ (r & 7)) * 16));
            acc[mt] = __builtin_amdgcn_mfma_f32_16x16x32_bf16(af, bf, acc[mt], 0, 0, 0);
        }
    };

    // prologue: fill the ring (8 DMA instrs in flight)
    issue_stage(0); issue_stage(1); issue_stage(2); issue_stage(3);

    // vmcnt(N) waits until only N vm-ops outstanding; stage s needs its own 2
    // instrs done. simm16: lgkmcnt=15 (0xF00) | expcnt=7 (0x70) | vmcnt low bits.
#define GEMM_STAGE(S, WN)                                   \
    {                                                       \
        __builtin_amdgcn_s_waitcnt(0x0F70 | (WN));          \
        compute_stage(S);                                   \
        if ((S) + DEPTH < NSTAGES) issue_stage((S) + DEPTH);\
    }
    GEMM_STAGE(0, 6) GEMM_STAGE(1, 6) GEMM_STAGE(2, 6) GEMM_STAGE(3, 6)
    GEMM_STAGE(4, 6) GEMM_STAGE(5, 4) GEMM_STAGE(6, 2) GEMM_STAGE(7, 0)
#undef GEMM_STAGE

    // epilogue: atomic accumulate partials (C/D layout: row = q*4+i, col = col)
#pragma unroll
    for (int mt = 0; mt < 4; mt++) {
#pragma unroll
        for (int i = 0; i < 4; i++) {
            const int t = mt * 16 + q * 4 + i;
            atomicAdd(out + (size_t)t * N_OUT + col, acc[mt][i]);
        }
    }
}

extern "C" void kernel_launch(void* const* d_in, const int* in_sizes, int n_in,
                              void* d_out, int out_size, void* d_ws, size_t ws_size,
                              hipStream_t stream) {
    const float* x      = (const float*)d_in[0];
    const int*   W      = (const int*)d_in[1];
    const float* scales = (const float*)d_in[2];
    const float* u      = (const float*)d_in[3];
    const float* bias   = (const float*)d_in[4];
    float* out = (float*)d_out;

    init_kernel<<<dim3(N_OUT / 4 / 256, T_TOK), 256, 0, stream>>>(x, u, bias, out);
    gemm_kernel<<<dim3(N_OUT / NCOLS, SPLITK), 256, 0, stream>>>(x, W, scales, out);
}